// Round 2
// baseline (69.410 us; speedup 1.0000x reference)
//
#include <hip/hip_runtime.h>

// EntropyBottleneck fused likelihood + quantize.
// out[0:N)   = (x/s_c + noise) * s_c
// out[N:2N)  = clamp(|sigmoid(sg*upper) - sigmoid(sg*lower)|, 1e-9), sg = -sign(l+u)

__device__ __forceinline__ float frcp(float x) { return __builtin_amdgcn_rcpf(x); }

__device__ __forceinline__ float ftanh(float x) {
    // tanh(x) = 1 - 2/(exp(2x)+1); exp overflow->inf->rcp->0 gives +1, underflow gives -1.
    float e = __expf(2.0f * x);
    return 1.0f - 2.0f * frcp(e + 1.0f);
}

__device__ __forceinline__ float fsigm(float x) {
    return frcp(1.0f + __expf(-x));
}

__device__ __forceinline__ float fsoftplus(float x) {
    return __logf(1.0f + __expf(x));
}

struct EBP {
    float m0[3], b0[3], t0[3];
    float m1[9], b1[3], t1[3];
    float m2[9], b2[3], t2[3];
    float m3[9], b3[3], t3[3];
    float m4[3], b4;
    float sc, inv;
};

__device__ __forceinline__ float logits_cum(const EBP& p, float v) {
    float h[3], g[3];
#pragma unroll
    for (int o = 0; o < 3; o++) {
        float l = fmaf(p.m0[o], v, p.b0[o]);
        h[o] = fmaf(p.t0[o], ftanh(l), l);
    }
#pragma unroll
    for (int o = 0; o < 3; o++) {
        float l = p.b1[o];
#pragma unroll
        for (int i = 0; i < 3; i++) l = fmaf(p.m1[o * 3 + i], h[i], l);
        g[o] = fmaf(p.t1[o], ftanh(l), l);
    }
#pragma unroll
    for (int o = 0; o < 3; o++) {
        float l = p.b2[o];
#pragma unroll
        for (int i = 0; i < 3; i++) l = fmaf(p.m2[o * 3 + i], g[i], l);
        h[o] = fmaf(p.t2[o], ftanh(l), l);
    }
#pragma unroll
    for (int o = 0; o < 3; o++) {
        float l = p.b3[o];
#pragma unroll
        for (int i = 0; i < 3; i++) l = fmaf(p.m3[o * 3 + i], h[i], l);
        g[o] = fmaf(p.t3[o], ftanh(l), l);
    }
    float out = p.b4;
#pragma unroll
    for (int i = 0; i < 3; i++) out = fmaf(p.m4[i], g[i], out);
    return out;
}

__device__ __forceinline__ void eb_elem(const EBP& p, float xs, float ns,
                                        float& q, float& lik) {
    float y = xs * p.inv;
    float l = logits_cum(p, y - 0.5f);
    float u = logits_cum(p, y + 0.5f);
    float sum = l + u;
    float sg = (sum > 0.0f) ? -1.0f : ((sum < 0.0f) ? 1.0f : 0.0f);
    float a = fsigm(sg * u);
    float b = fsigm(sg * l);
    q = (y + ns) * p.sc;
    lik = fmaxf(fabsf(a - b), 1e-9f);
}

__global__ __launch_bounds__(256) void eb_kernel(
    const float* __restrict__ x, const float* __restrict__ nz,
    const float* __restrict__ s,
    const float* __restrict__ m0_, const float* __restrict__ b0_, const float* __restrict__ f0_,
    const float* __restrict__ m1_, const float* __restrict__ b1_, const float* __restrict__ f1_,
    const float* __restrict__ m2_, const float* __restrict__ b2_, const float* __restrict__ f2_,
    const float* __restrict__ m3_, const float* __restrict__ b3_, const float* __restrict__ f3_,
    const float* __restrict__ m4_, const float* __restrict__ b4_,
    float* __restrict__ out, int n)
{
    EBP p;
#pragma unroll
    for (int i = 0; i < 3; i++) { p.m0[i] = fsoftplus(m0_[i]); p.b0[i] = b0_[i]; p.t0[i] = ftanh(f0_[i]); }
#pragma unroll
    for (int i = 0; i < 9; i++) p.m1[i] = fsoftplus(m1_[i]);
#pragma unroll
    for (int i = 0; i < 3; i++) { p.b1[i] = b1_[i]; p.t1[i] = ftanh(f1_[i]); }
#pragma unroll
    for (int i = 0; i < 9; i++) p.m2[i] = fsoftplus(m2_[i]);
#pragma unroll
    for (int i = 0; i < 3; i++) { p.b2[i] = b2_[i]; p.t2[i] = ftanh(f2_[i]); }
#pragma unroll
    for (int i = 0; i < 9; i++) p.m3[i] = fsoftplus(m3_[i]);
#pragma unroll
    for (int i = 0; i < 3; i++) { p.b3[i] = b3_[i]; p.t3[i] = ftanh(f3_[i]); }
#pragma unroll
    for (int i = 0; i < 3; i++) p.m4[i] = fsoftplus(m4_[i]);
    p.b4 = b4_[0];
    p.sc = fmaxf(s[0], 1e-4f);
    p.inv = 1.0f / p.sc;   // accurate, once per thread

    float* __restrict__ oq = out;
    float* __restrict__ ol = out + n;

    const int nvec = n >> 2;
    const int stride = gridDim.x * blockDim.x;
    const float4* __restrict__ x4 = (const float4*)x;
    const float4* __restrict__ n4 = (const float4*)nz;

    for (int i = blockIdx.x * blockDim.x + threadIdx.x; i < nvec; i += stride) {
        float4 xv = x4[i];
        float4 nv = n4[i];
        float4 qv, lv;
        const float* xs = (const float*)&xv;
        const float* ns = (const float*)&nv;
        float* qs = (float*)&qv;
        float* ls = (float*)&lv;
#pragma unroll
        for (int j = 0; j < 4; j++) {
            eb_elem(p, xs[j], ns[j], qs[j], ls[j]);
        }
        ((float4*)oq)[i] = qv;
        ((float4*)ol)[i] = lv;
    }

    // tail (n not divisible by 4) — not hit for N=8388608 but keep it correct
    const int rem = n & 3;
    if (rem) {
        const int base = nvec << 2;
        const int t = blockIdx.x * blockDim.x + threadIdx.x;
        if (t < rem) {
            const int idx = base + t;
            float q, lk;
            eb_elem(p, x[idx], nz[idx], q, lk);
            oq[idx] = q;
            ol[idx] = lk;
        }
    }
}

extern "C" void kernel_launch(void* const* d_in, const int* in_sizes, int n_in,
                              void* d_out, int out_size, void* d_ws, size_t ws_size,
                              hipStream_t stream) {
    const float* x  = (const float*)d_in[0];
    const float* nz = (const float*)d_in[1];
    const float* s  = (const float*)d_in[2];
    const float* m0 = (const float*)d_in[3];
    const float* b0 = (const float*)d_in[4];
    const float* f0 = (const float*)d_in[5];
    const float* m1 = (const float*)d_in[6];
    const float* b1 = (const float*)d_in[7];
    const float* f1 = (const float*)d_in[8];
    const float* m2 = (const float*)d_in[9];
    const float* b2 = (const float*)d_in[10];
    const float* f2 = (const float*)d_in[11];
    const float* m3 = (const float*)d_in[12];
    const float* b3 = (const float*)d_in[13];
    const float* f3 = (const float*)d_in[14];
    const float* m4 = (const float*)d_in[15];
    const float* b4 = (const float*)d_in[16];
    const int n = in_sizes[0];

    const int blocks = 2048;   // grid-stride; 4 float4 iters/thread at N=8.4M
    eb_kernel<<<blocks, 256, 0, stream>>>(x, nz, s,
                                          m0, b0, f0, m1, b1, f1,
                                          m2, b2, f2, m3, b3, f3,
                                          m4, b4,
                                          (float*)d_out, n);
}

// Round 3
// 32.694 us; speedup vs baseline: 2.1230x; 2.1230x over previous
//
#include <hip/hip_runtime.h>

// EntropyBottleneck fused likelihood + quantize, table-driven.
// likelihood(y) is a scalar function of y = x/s_c only (58 shared params),
// so: kernel 1 tabulates F(y) at 4096 points over [-16,16] into d_ws;
// kernel 2 (memory-bound) does q=(y+noise)*sc and lik=lerp(table).

#define NT   4096
#define TLO  (-16.0f)
#define THI  ( 16.0f)

__device__ __forceinline__ float frcp(float x) { return __builtin_amdgcn_rcpf(x); }

__device__ __forceinline__ float ftanh(float x) {
    float e = __expf(2.0f * x);
    return 1.0f - 2.0f * frcp(e + 1.0f);
}

__device__ __forceinline__ float fsigm(float x) {
    return frcp(1.0f + __expf(-x));
}

__device__ __forceinline__ float fsoftplus(float x) {
    return __logf(1.0f + __expf(x));
}

struct EBP {
    float m0[3], b0[3], t0[3];
    float m1[9], b1[3], t1[3];
    float m2[9], b2[3], t2[3];
    float m3[9], b3[3], t3[3];
    float m4[3], b4;
    float sc, inv;
};

__device__ __forceinline__ void load_params(
    EBP& p,
    const float* s,
    const float* m0_, const float* b0_, const float* f0_,
    const float* m1_, const float* b1_, const float* f1_,
    const float* m2_, const float* b2_, const float* f2_,
    const float* m3_, const float* b3_, const float* f3_,
    const float* m4_, const float* b4_)
{
#pragma unroll
    for (int i = 0; i < 3; i++) { p.m0[i] = fsoftplus(m0_[i]); p.b0[i] = b0_[i]; p.t0[i] = ftanh(f0_[i]); }
#pragma unroll
    for (int i = 0; i < 9; i++) p.m1[i] = fsoftplus(m1_[i]);
#pragma unroll
    for (int i = 0; i < 3; i++) { p.b1[i] = b1_[i]; p.t1[i] = ftanh(f1_[i]); }
#pragma unroll
    for (int i = 0; i < 9; i++) p.m2[i] = fsoftplus(m2_[i]);
#pragma unroll
    for (int i = 0; i < 3; i++) { p.b2[i] = b2_[i]; p.t2[i] = ftanh(f2_[i]); }
#pragma unroll
    for (int i = 0; i < 9; i++) p.m3[i] = fsoftplus(m3_[i]);
#pragma unroll
    for (int i = 0; i < 3; i++) { p.b3[i] = b3_[i]; p.t3[i] = ftanh(f3_[i]); }
#pragma unroll
    for (int i = 0; i < 3; i++) p.m4[i] = fsoftplus(m4_[i]);
    p.b4 = b4_[0];
    p.sc = fmaxf(s[0], 1e-4f);
    p.inv = 1.0f / p.sc;
}

__device__ __forceinline__ float logits_cum(const EBP& p, float v) {
    float h[3], g[3];
#pragma unroll
    for (int o = 0; o < 3; o++) {
        float l = fmaf(p.m0[o], v, p.b0[o]);
        h[o] = fmaf(p.t0[o], ftanh(l), l);
    }
#pragma unroll
    for (int o = 0; o < 3; o++) {
        float l = p.b1[o];
#pragma unroll
        for (int i = 0; i < 3; i++) l = fmaf(p.m1[o * 3 + i], h[i], l);
        g[o] = fmaf(p.t1[o], ftanh(l), l);
    }
#pragma unroll
    for (int o = 0; o < 3; o++) {
        float l = p.b2[o];
#pragma unroll
        for (int i = 0; i < 3; i++) l = fmaf(p.m2[o * 3 + i], g[i], l);
        h[o] = fmaf(p.t2[o], ftanh(l), l);
    }
#pragma unroll
    for (int o = 0; o < 3; o++) {
        float l = p.b3[o];
#pragma unroll
        for (int i = 0; i < 3; i++) l = fmaf(p.m3[o * 3 + i], h[i], l);
        g[o] = fmaf(p.t3[o], ftanh(l), l);
    }
    float out = p.b4;
#pragma unroll
    for (int i = 0; i < 3; i++) out = fmaf(p.m4[i], g[i], out);
    return out;
}

__device__ __forceinline__ float eb_lik(const EBP& p, float y) {
    float l = logits_cum(p, y - 0.5f);
    float u = logits_cum(p, y + 0.5f);
    float sum = l + u;
    float sg = (sum > 0.0f) ? -1.0f : ((sum < 0.0f) ? 1.0f : 0.0f);
    float a = fsigm(sg * u);
    float b = fsigm(sg * l);
    return fmaxf(fabsf(a - b), 1e-9f);
}

// ---- kernel 1: tabulate F(y) into d_ws ----
__global__ __launch_bounds__(256) void eb_build_table(
    const float* __restrict__ s,
    const float* __restrict__ m0_, const float* __restrict__ b0_, const float* __restrict__ f0_,
    const float* __restrict__ m1_, const float* __restrict__ b1_, const float* __restrict__ f1_,
    const float* __restrict__ m2_, const float* __restrict__ b2_, const float* __restrict__ f2_,
    const float* __restrict__ m3_, const float* __restrict__ b3_, const float* __restrict__ f3_,
    const float* __restrict__ m4_, const float* __restrict__ b4_,
    float* __restrict__ table)
{
    int idx = blockIdx.x * blockDim.x + threadIdx.x;
    if (idx >= NT) return;
    EBP p;
    load_params(p, s, m0_, b0_, f0_, m1_, b1_, f1_, m2_, b2_, f2_, m3_, b3_, f3_, m4_, b4_);
    const float hstep = (THI - TLO) / (float)(NT - 1);
    float y = TLO + (float)idx * hstep;
    table[idx] = eb_lik(p, y);
}

// ---- kernel 2: memory-bound main pass ----
__global__ __launch_bounds__(256) void eb_main(
    const float* __restrict__ x, const float* __restrict__ nz,
    const float* __restrict__ s, const float* __restrict__ table,
    float* __restrict__ out, int n)
{
    __shared__ float tab[NT];
    {
        float4* t4 = (float4*)tab;
        const float4* g4 = (const float4*)table;
        for (int i = threadIdx.x; i < NT / 4; i += blockDim.x) t4[i] = g4[i];
    }
    __syncthreads();

    const float sc = fmaxf(s[0], 1e-4f);
    const float inv = 1.0f / sc;
    const float invh = (float)(NT - 1) / (THI - TLO);

    float* __restrict__ oq = out;
    float* __restrict__ ol = out + n;

    const int nvec = n >> 2;
    const int stride = gridDim.x * blockDim.x;
    const float4* __restrict__ x4 = (const float4*)x;
    const float4* __restrict__ n4 = (const float4*)nz;

    for (int i = blockIdx.x * blockDim.x + threadIdx.x; i < nvec; i += stride) {
        float4 xv = x4[i];
        float4 nv = n4[i];
        float4 qv, lv;
        const float* xs = (const float*)&xv;
        const float* ns = (const float*)&nv;
        float* qs = (float*)&qv;
        float* ls = (float*)&lv;
#pragma unroll
        for (int j = 0; j < 4; j++) {
            float y = xs[j] * inv;
            qs[j] = (y + ns[j]) * sc;
            float t = (y - TLO) * invh;
            t = fminf(fmaxf(t, 0.0f), (float)(NT - 1) - 1e-3f);
            float fi = floorf(t);
            float frac = t - fi;
            int idx = (int)fi;
            float f0 = tab[idx];
            float f1 = tab[idx + 1];
            ls[j] = fmaxf(fmaf(frac, f1 - f0, f0), 1e-9f);
        }
        ((float4*)oq)[i] = qv;
        ((float4*)ol)[i] = lv;
    }

    const int rem = n & 3;
    if (rem) {
        const int base = nvec << 2;
        const int t0 = blockIdx.x * blockDim.x + threadIdx.x;
        if (t0 < rem) {
            const int idx = base + t0;
            float y = x[idx] * inv;
            oq[idx] = (y + nz[idx]) * sc;
            float t = (y - TLO) * invh;
            t = fminf(fmaxf(t, 0.0f), (float)(NT - 1) - 1e-3f);
            float fi = floorf(t);
            int ii = (int)fi;
            float f0 = tab[ii];
            float f1 = tab[ii + 1];
            ol[idx] = fmaxf(fmaf(t - fi, f1 - f0, f0), 1e-9f);
        }
    }
}

// ---- fallback: direct per-element evaluation (if ws too small) ----
__global__ __launch_bounds__(256) void eb_direct(
    const float* __restrict__ x, const float* __restrict__ nz,
    const float* __restrict__ s,
    const float* __restrict__ m0_, const float* __restrict__ b0_, const float* __restrict__ f0_,
    const float* __restrict__ m1_, const float* __restrict__ b1_, const float* __restrict__ f1_,
    const float* __restrict__ m2_, const float* __restrict__ b2_, const float* __restrict__ f2_,
    const float* __restrict__ m3_, const float* __restrict__ b3_, const float* __restrict__ f3_,
    const float* __restrict__ m4_, const float* __restrict__ b4_,
    float* __restrict__ out, int n)
{
    EBP p;
    load_params(p, s, m0_, b0_, f0_, m1_, b1_, f1_, m2_, b2_, f2_, m3_, b3_, f3_, m4_, b4_);
    float* __restrict__ oq = out;
    float* __restrict__ ol = out + n;
    const int stride = gridDim.x * blockDim.x;
    for (int i = blockIdx.x * blockDim.x + threadIdx.x; i < n; i += stride) {
        float y = x[i] * p.inv;
        oq[i] = (y + nz[i]) * p.sc;
        ol[i] = eb_lik(p, y);
    }
}

extern "C" void kernel_launch(void* const* d_in, const int* in_sizes, int n_in,
                              void* d_out, int out_size, void* d_ws, size_t ws_size,
                              hipStream_t stream) {
    const float* x  = (const float*)d_in[0];
    const float* nz = (const float*)d_in[1];
    const float* s  = (const float*)d_in[2];
    const float* m0 = (const float*)d_in[3];
    const float* b0 = (const float*)d_in[4];
    const float* f0 = (const float*)d_in[5];
    const float* m1 = (const float*)d_in[6];
    const float* b1 = (const float*)d_in[7];
    const float* f1 = (const float*)d_in[8];
    const float* m2 = (const float*)d_in[9];
    const float* b2 = (const float*)d_in[10];
    const float* f2 = (const float*)d_in[11];
    const float* m3 = (const float*)d_in[12];
    const float* b3 = (const float*)d_in[13];
    const float* f3 = (const float*)d_in[14];
    const float* m4 = (const float*)d_in[15];
    const float* b4 = (const float*)d_in[16];
    const int n = in_sizes[0];

    if (ws_size >= (size_t)(NT * sizeof(float))) {
        float* table = (float*)d_ws;
        eb_build_table<<<NT / 256, 256, 0, stream>>>(
            s, m0, b0, f0, m1, b1, f1, m2, b2, f2, m3, b3, f3, m4, b4, table);
        eb_main<<<2048, 256, 0, stream>>>(x, nz, s, table, (float*)d_out, n);
    } else {
        eb_direct<<<2048, 256, 0, stream>>>(
            x, nz, s, m0, b0, f0, m1, b1, f1, m2, b2, f2, m3, b3, f3, m4, b4,
            (float*)d_out, n);
    }
}